// Round 1
// baseline (651.407 us; speedup 1.0000x reference)
//
#include <hip/hip_runtime.h>

// Problem constants (fixed by reference)
#define HH   480
#define WW   640
#define HWP  (HH*WW)      // 307200
#define NSEM 12
#define NINS 16
#define NCH  28           // sem channels then ins channels

typedef _Float16 f16_t;

union P32  { f16_t h[32]; int4 v[4]; };   // one pixel's channels-last record (64 B)
union I4H8 { int4 v; f16_t h[8]; };
union I2H4 { int2 v; f16_t h[4]; };

// 13-tap Gaussian (sigma=3, r=6)
__device__ __forceinline__ void gauss13(float k[13]) {
    float s = 0.f;
#pragma unroll
    for (int j = 0; j < 13; ++j) {
        float xx = (float)(j - 6);
        float v  = __expf(-(xx * xx) * (1.f / 18.f));
        k[j] = v; s += v;
    }
    float inv = 1.f / s;
#pragma unroll
    for (int j = 0; j < 13; ++j) k[j] *= inv;
}

template <int N>
__device__ __forceinline__ void softmaxN(const float* __restrict__ in, float* __restrict__ out) {
    float m = in[0];
#pragma unroll
    for (int i = 1; i < N; ++i) m = fmaxf(m, in[i]);
    float s = 0.f;
#pragma unroll
    for (int i = 0; i < N; ++i) { float e = __expf(in[i] - m); out[i] = e; s += e; }
    float inv = 1.f / s;
#pragma unroll
    for (int i = 0; i < N; ++i) out[i] *= inv;
}

// ---------------------------------------------------------------------------
// Init: softmax(logits) -> qcl (channels-last f16 record) and lcl (logits as
// channels-last f16 record). No plane-major copies anywhere anymore.
// ---------------------------------------------------------------------------
__global__ __launch_bounds__(256) void init_kernel(const float* __restrict__ semL,
                                                   const float* __restrict__ insL,
                                                   int4* __restrict__ qcl4,
                                                   int4* __restrict__ lcl4) {
    int p = blockIdx.x * 256 + threadIdx.x;
    float v[NINS], o[NINS];
    P32 pk, lk;
#pragma unroll
    for (int i = 0; i < 32; ++i) { pk.h[i] = (f16_t)0.f; lk.h[i] = (f16_t)0.f; }
#pragma unroll
    for (int i = 0; i < NSEM; ++i) { v[i] = semL[i * HWP + p]; lk.h[i] = (f16_t)v[i]; }
    softmaxN<NSEM>(v, o);
#pragma unroll
    for (int i = 0; i < NSEM; ++i) pk.h[i] = (f16_t)o[i];
#pragma unroll
    for (int i = 0; i < NINS; ++i) { v[i] = insL[i * HWP + p]; lk.h[NSEM + i] = (f16_t)v[i]; }
    softmaxN<NINS>(v, o);
#pragma unroll
    for (int i = 0; i < NINS; ++i) pk.h[NSEM + i] = (f16_t)o[i];
#pragma unroll
    for (int j = 0; j < 4; ++j) { qcl4[(size_t)p * 4 + j] = pk.v[j]; lcl4[(size_t)p * 4 + j] = lk.v[j]; }
}

// ---------------------------------------------------------------------------
// Horizontal 13-tap pass (zero pad), channels-last. One thread per 16-B
// quarter-record: 13 b128 loads (L1-resident window) + 104 mix-FMA + 1 store.
// No LDS, no sync, fully coalesced.
// ---------------------------------------------------------------------------
__global__ __launch_bounds__(256) void hpass_kernel(const int4* __restrict__ qcl4,
                                                    int4* __restrict__ hq4) {
    int tid = blockIdx.x * 256 + threadIdx.x;   // quarter-record index
    int p = tid >> 2;
    int s = tid & 3;
    int y = p / WW;
    int x = p - y * WW;
    float k[13]; gauss13(k);
    float a[8];
#pragma unroll
    for (int i = 0; i < 8; ++i) a[i] = 0.f;
#pragma unroll
    for (int t = 0; t < 13; ++t) {
        int xt = x + t - 6;
        if ((unsigned)xt < WW) {                 // conv zero-pad outside row
            I4H8 u; u.v = qcl4[(size_t)(p + t - 6) * 4 + s];
#pragma unroll
            for (int i = 0; i < 8; ++i) a[i] = fmaf((float)u.h[i], k[t], a[i]);
        }
    }
    I4H8 r;
#pragma unroll
    for (int i = 0; i < 8; ++i) r.h[i] = (f16_t)a[i];
    hq4[tid] = r.v;
}

// ---------------------------------------------------------------------------
// Fused iteration kernel: vertical blur pass (from hq, global/L2) + bilateral
// (LDS window, fused weight+gather) + CRF pointwise tail. 32x8 tile, 1 px/thr.
// ---------------------------------------------------------------------------
#define TTW 32
#define TTH 8
#define TWW (TTW + 4)         // 36
#define TWH (TTH + 4)         // 12
#define TWN (TWW * TWH)       // 432

template <bool LAST>
__global__ __launch_bounds__(256, 4) void tail_kernel(const int4* __restrict__ qcl4,
                                                      const int4* __restrict__ hq4,
                                                      const float* __restrict__ img,
                                                      const int4* __restrict__ lcl4,
                                                      const float* __restrict__ sem_sw,
                                                      const float* __restrict__ sem_bw,
                                                      const float* __restrict__ sem_compat,
                                                      const float* __restrict__ ins_sw,
                                                      const float* __restrict__ ins_bw,
                                                      const int*   __restrict__ labels,
                                                      const float* __restrict__ cross_is,
                                                      const float* __restrict__ cross_si,
                                                      int4* __restrict__ qclo4,
                                                      float* __restrict__ dout) {
    __shared__ int4  lqA[TWN * 3];       // 20736 B (channels 0..23)
    __shared__ int2  lqB[TWN];           //  3456 B (channels 24..27)
    __shared__ float limg[3 * TWN];      //  5184 B
    __shared__ float sC[NSEM * NSEM];
    __shared__ float sMis[NINS * NSEM];
    __shared__ float sMsi[NINS * NSEM];
    __shared__ float sws[NSEM], sbs[NSEM], swi[NINS], sbi[NINS];

    const int t = threadIdx.x;
    // XCD-chunked swizzle (1200 blocks, 8 XCDs -> 150-consecutive-tile stripes):
    // vertically adjacent tiles share 6-row hq halos -> keep them on one L2.
    const int lid = (int)blockIdx.x;
    const int swz = (lid & 7) * 150 + (lid >> 3);
    const int by  = swz / 20;
    const int bx  = swz - by * 20;
    const int tx  = t & 31;
    const int ty  = t >> 5;
    const int x0  = bx * TTW;
    const int y0  = by * TTH;
    const int p   = (y0 + ty) * WW + (x0 + tx);

    if (t < NSEM * NSEM) sC[t] = sem_compat[t];
    if (t < NINS * NSEM) {
        int i = t / NSEM, o = t - i * NSEM;
        sMis[t] = cross_is[labels[i] * NSEM + o];
        sMsi[t] = cross_si[labels[i] * NSEM + o];  // [o_ins*12 + i_sem]
    }
    if (t < NSEM) { sws[t] = sem_sw[t]; sbs[t] = sem_bw[t]; }
    if (t < NINS) { int l = labels[t]; swi[t] = ins_sw[l]; sbi[t] = ins_bw[l]; }

    // stage bilateral q window (edge-clamped), A-part: idx = e*3+s
#pragma unroll
    for (int j = 0; j < 6; ++j) {
        int idx = t + j * 256;
        if (idx < TWN * 3) {
            int e = idx / 3, s = idx - e * 3;
            int ly = e / TWW, lx = e - ly * TWW;
            int gy = min(max(y0 - 2 + ly, 0), HH - 1);
            int gx = min(max(x0 - 2 + lx, 0), WW - 1);
            lqA[idx] = qcl4[((size_t)gy * WW + gx) * 4 + s];
        }
    }
    // B-part: channels 24..27 = int2 #6 of the 64-B record
#pragma unroll
    for (int j = 0; j < 2; ++j) {
        int e = t + j * 256;
        if (e < TWN) {
            int ly = e / TWW, lx = e - ly * TWW;
            int gy = min(max(y0 - 2 + ly, 0), HH - 1);
            int gx = min(max(x0 - 2 + lx, 0), WW - 1);
            lqB[e] = ((const int2*)qcl4)[((size_t)gy * WW + gx) * 8 + 6];
        }
    }
    // image window (fp32, edge-clamped)
    for (int idx = t; idx < 3 * TWN; idx += 256) {
        int cc  = idx / TWN;
        int rem = idx - cc * TWN;
        int ly  = rem / TWW, lx = rem - ly * TWW;
        int gy  = min(max(y0 - 2 + ly, 0), HH - 1);
        int gx  = min(max(x0 - 2 + lx, 0), WW - 1);
        limg[idx] = img[(size_t)cc * HWP + gy * WW + gx];
    }

    // ---- vertical blur pass: 13 coalesced record reads/px from hq (zero pad
    // rows outside image), f32 accumulate. Runs before the barrier so it
    // overlaps the LDS staging latency of the other waves.
    float kv[13]; gauss13(kv);
    float vac[NCH];
#pragma unroll
    for (int c = 0; c < NCH; ++c) vac[c] = 0.f;
    {
        const int xc = x0 + tx;
        const int yb = y0 + ty - 6;
#pragma unroll
        for (int tt = 0; tt < 13; ++tt) {
            int yt = yb + tt;
            if ((unsigned)yt < HH) {
                const int4* rp = &hq4[((size_t)yt * WW + xc) * 4];
                float w = kv[tt];
                I4H8 u0, u1, u2; I2H4 u3;
                u0.v = rp[0]; u1.v = rp[1]; u2.v = rp[2];
                u3.v = ((const int2*)rp)[6];
#pragma unroll
                for (int i = 0; i < 8; ++i) vac[i]      = fmaf((float)u0.h[i], w, vac[i]);
#pragma unroll
                for (int i = 0; i < 8; ++i) vac[8 + i]  = fmaf((float)u1.h[i], w, vac[8 + i]);
#pragma unroll
                for (int i = 0; i < 8; ++i) vac[16 + i] = fmaf((float)u2.h[i], w, vac[16 + i]);
#pragma unroll
                for (int i = 0; i < 4; ++i) vac[24 + i] = fmaf((float)u3.h[i], w, vac[24 + i]);
            }
        }
    }
    // own-pixel logits record; issue before the barrier to hide latency
    I4H8 l0, l1, l2; I2H4 l3;
    l0.v = lcl4[(size_t)p * 4 + 0];
    l1.v = lcl4[(size_t)p * 4 + 1];
    l2.v = lcl4[(size_t)p * 4 + 2];
    l3.v = ((const int2*)lcl4)[(size_t)p * 8 + 6];
    __syncthreads();

    // ---- fused bilateral: weight + gather + den in one 25-tap loop
    // (no wnr[25] array -> ~25 fewer live VGPRs, normalize by 1/den at end)
    float num[NCH];
#pragma unroll
    for (int c = 0; c < NCH; ++c) num[c] = 0.f;
    float den = 0.f;
    {
        const int wc = (ty + 2) * TWW + (tx + 2);
        float i0 = limg[wc], i1 = limg[TWN + wc], i2 = limg[2 * TWN + wc];
#pragma unroll
        for (int dy = 0; dy < 5; ++dy) {
#pragma unroll
            for (int dx = 0; dx < 5; ++dx) {
                int e = (ty + dy) * TWW + (tx + dx);
                float d0 = limg[e] - i0;
                float d1 = limg[TWN + e] - i1;
                float d2 = limg[2 * TWN + e] - i2;
                float cd = d0 * d0 + d1 * d1 + d2 * d2;
                float sd = (float)((dy - 2) * (dy - 2) + (dx - 2) * (dx - 2));
                float w  = __expf(-sd * (1.f / 18.f) - cd * (1.f / 0.045f));
                den += w;
                I4H8 a0, a1, a2; I2H4 b;
                a0.v = lqA[e * 3 + 0]; a1.v = lqA[e * 3 + 1]; a2.v = lqA[e * 3 + 2];
                b.v  = lqB[e];
#pragma unroll
                for (int i = 0; i < 8; ++i) num[i]      = fmaf((float)a0.h[i], w, num[i]);
#pragma unroll
                for (int i = 0; i < 8; ++i) num[8 + i]  = fmaf((float)a1.h[i], w, num[8 + i]);
#pragma unroll
                for (int i = 0; i < 8; ++i) num[16 + i] = fmaf((float)a2.h[i], w, num[16 + i]);
#pragma unroll
                for (int i = 0; i < 4; ++i) num[24 + i] = fmaf((float)b.h[i],  w, num[24 + i]);
            }
        }
    }
    const float inv = 1.f / den;

    // ---- pointwise CRF tail
    float comb[NSEM];
#pragma unroll
    for (int i = 0; i < NSEM; ++i)
        comb[i] = sws[i] * vac[i] + sbs[i] * (num[i] * inv);
    float ts[NSEM];
#pragma unroll
    for (int o = 0; o < NSEM; ++o) {
        float a = (o < 8) ? (float)l0.h[o] : (float)l1.h[o - 8];
#pragma unroll
        for (int i = 0; i < NSEM; ++i) a = fmaf(sC[i * NSEM + o], comb[i], a);
        ts[o] = a;
    }
    float ti[NINS];
#pragma unroll
    for (int i = 0; i < NINS; ++i) {
        const int c = NSEM + i;   // 12..27
        float lg = (c < 16) ? (float)l1.h[c - 8]
                 : (c < 24) ? (float)l2.h[c - 16]
                            : (float)l3.h[c - 24];
        ti[i] = lg + swi[i] * vac[c] + sbi[i] * (num[c] * inv);
    }

    float sIns[NINS], sSem[NSEM];
    softmaxN<NINS>(ti, sIns);
    softmaxN<NSEM>(ts, sSem);

    float nts[NSEM];
#pragma unroll
    for (int o = 0; o < NSEM; ++o) {
        float a = ts[o];
#pragma unroll
        for (int i = 0; i < NINS; ++i) a = fmaf(sMis[i * NSEM + o], sIns[i], a);
        nts[o] = a;
    }
    float nti[NINS];
#pragma unroll
    for (int o = 0; o < NINS; ++o) {
        float a = ti[o];
#pragma unroll
        for (int i = 0; i < NSEM; ++i) a = fmaf(sMsi[o * NSEM + i], sSem[i], a);
        nti[o] = a;
    }

    float oq1[NSEM], oq2[NINS];
    softmaxN<NSEM>(nts, oq1);
    softmaxN<NINS>(nti, oq2);

    if (LAST) {
#pragma unroll
        for (int i = 0; i < NSEM; ++i) dout[i * HWP + p] = oq1[i];
#pragma unroll
        for (int i = 0; i < NINS; ++i) dout[(NSEM + i) * HWP + p] = oq2[i];
    } else {
        P32 pk;
#pragma unroll
        for (int i = 0; i < 32; ++i) pk.h[i] = (f16_t)0.f;
#pragma unroll
        for (int i = 0; i < NSEM; ++i) pk.h[i] = (f16_t)oq1[i];
#pragma unroll
        for (int i = 0; i < NINS; ++i) pk.h[NSEM + i] = (f16_t)oq2[i];
#pragma unroll
        for (int j = 0; j < 4; ++j) qclo4[(size_t)p * 4 + j] = pk.v[j];
    }
}

// ---------------------------------------------------------------------------
extern "C" void kernel_launch(void* const* d_in, const int* in_sizes, int n_in,
                              void* d_out, int out_size, void* d_ws, size_t ws_size,
                              hipStream_t stream) {
    const float* image      = (const float*)d_in[0];
    const float* semL       = (const float*)d_in[1];
    const float* insL       = (const float*)d_in[2];
    const int*   labels     = (const int*)  d_in[3];
    const float* sem_sw     = (const float*)d_in[4];
    const float* sem_bw     = (const float*)d_in[5];
    const float* sem_compat = (const float*)d_in[6];
    const float* ins_sw     = (const float*)d_in[7];
    const float* ins_bw     = (const float*)d_in[8];
    const float* cross_is   = (const float*)d_in[9];
    const float* cross_si   = (const float*)d_in[10];

    // Workspace: qclA | qclB | hq | lcl   (all 64-B channels-last records)
    char* ws = (char*)d_ws;
    int4* qclA = (int4*)ws;   ws += (size_t)HWP * 64;
    int4* qclB = (int4*)ws;   ws += (size_t)HWP * 64;
    int4* hq   = (int4*)ws;   ws += (size_t)HWP * 64;
    int4* lcl  = (int4*)ws;

    const int PIX_BLOCKS = HWP / 256;       // 1200
    const int HB         = HWP * 4 / 256;   // 4800 (quarter-records)

    init_kernel<<<PIX_BLOCKS, 256, 0, stream>>>(semL, insL, qclA, lcl);

    // iter 0: A -> B
    hpass_kernel<<<HB, 256, 0, stream>>>(qclA, hq);
    tail_kernel<false><<<1200, 256, 0, stream>>>(qclA, hq, image, lcl,
                                                 sem_sw, sem_bw, sem_compat,
                                                 ins_sw, ins_bw, labels,
                                                 cross_is, cross_si, qclB, nullptr);
    // iter 1: B -> A
    hpass_kernel<<<HB, 256, 0, stream>>>(qclB, hq);
    tail_kernel<false><<<1200, 256, 0, stream>>>(qclB, hq, image, lcl,
                                                 sem_sw, sem_bw, sem_compat,
                                                 ins_sw, ins_bw, labels,
                                                 cross_is, cross_si, qclA, nullptr);
    // iter 2: A -> d_out (fp32 plane-major)
    hpass_kernel<<<HB, 256, 0, stream>>>(qclA, hq);
    tail_kernel<true><<<1200, 256, 0, stream>>>(qclA, hq, image, lcl,
                                                sem_sw, sem_bw, sem_compat,
                                                ins_sw, ins_bw, labels,
                                                cross_is, cross_si, nullptr, (float*)d_out);
}

// Round 2
// 356.227 us; speedup vs baseline: 1.8286x; 1.8286x over previous
//
#include <hip/hip_runtime.h>

// Problem constants (fixed by reference)
#define HH   480
#define WW   640
#define HWP  (HH*WW)      // 307200
#define NSEM 12
#define NINS 16
#define NCH  28           // sem channels then ins channels

typedef _Float16 f16_t;

union P32  { f16_t h[32]; int4 v[4]; };      // one pixel's channels-last record
union I4H8 { int4 v; f16_t h[8]; };
union I2H4 { int2 v; f16_t h[4]; };
union H4I2 { f16_t h[4]; int2 v; };

// 13-tap Gaussian (sigma=3, r=6)
__device__ __forceinline__ void gauss13(float k[13]) {
    float s = 0.f;
#pragma unroll
    for (int j = 0; j < 13; ++j) {
        float xx = (float)(j - 6);
        float v  = __expf(-(xx * xx) * (1.f / 18.f));
        k[j] = v; s += v;
    }
    float inv = 1.f / s;
#pragma unroll
    for (int j = 0; j < 13; ++j) k[j] *= inv;
}

template <int N>
__device__ __forceinline__ void softmaxN(const float* __restrict__ in, float* __restrict__ out) {
    float m = in[0];
#pragma unroll
    for (int i = 1; i < N; ++i) m = fmaxf(m, in[i]);
    float s = 0.f;
#pragma unroll
    for (int i = 0; i < N; ++i) { float e = __expf(in[i] - m); out[i] = e; s += e; }
    float inv = 1.f / s;
#pragma unroll
    for (int i = 0; i < N; ++i) out[i] *= inv;
}

// ---------------------------------------------------------------------------
// Init: softmax(logits) -> qcl (channels-last f16) + qpm (plane f16),
// plus f16 copies of the logits (plane-major)
// ---------------------------------------------------------------------------
__global__ __launch_bounds__(256) void init_kernel(const float* __restrict__ semL,
                                                   const float* __restrict__ insL,
                                                   int4* __restrict__ qcl4,
                                                   f16_t* __restrict__ qpm,
                                                   f16_t* __restrict__ semLh,
                                                   f16_t* __restrict__ insLh) {
    int p = blockIdx.x * 256 + threadIdx.x;
    float v[NINS], o[NINS];
    P32 pk;
#pragma unroll
    for (int i = 0; i < 32; ++i) pk.h[i] = (f16_t)0.f;
#pragma unroll
    for (int i = 0; i < NSEM; ++i) { v[i] = semL[i * HWP + p]; semLh[i * HWP + p] = (f16_t)v[i]; }
    softmaxN<NSEM>(v, o);
#pragma unroll
    for (int i = 0; i < NSEM; ++i) { f16_t h = (f16_t)o[i]; pk.h[i] = h; qpm[i * HWP + p] = h; }
#pragma unroll
    for (int i = 0; i < NINS; ++i) { v[i] = insL[i * HWP + p]; insLh[i * HWP + p] = (f16_t)v[i]; }
    softmaxN<NINS>(v, o);
#pragma unroll
    for (int i = 0; i < NINS; ++i) { f16_t h = (f16_t)o[i]; pk.h[NSEM + i] = h; qpm[(NSEM + i) * HWP + p] = h; }
#pragma unroll
    for (int j = 0; j < 4; ++j) qcl4[p * 4 + j] = pk.v[j];
}

// ---------------------------------------------------------------------------
// Fused separable 13x13 blur (zero pad), LDS-tiled 64x32, f16 in/out.
// f16 LDS buffers: 12.7 KB total (was 25.3 KB) -> ~2x occupancy headroom.
// f16 h-pass intermediate validated in round 1 (absmax unchanged).
// ---------------------------------------------------------------------------
#define BTW 64
#define BTH 32
#define RAWW 80                    // halo 8 left/right, 16-B aligned rows
#define RAWH 44                    // halo 6 top/bottom
__global__ __launch_bounds__(256, 6) void blur_fused_kernel(const f16_t* __restrict__ in,
                                                            f16_t* __restrict__ out) {
    __shared__ __align__(16) f16_t rawh[RAWH * RAWW];   // 7040 B
    __shared__ __align__(16) f16_t hbh[RAWH * BTW];     // 5632 B
    const int t  = threadIdx.x;
    const int x0 = blockIdx.x * BTW;
    const int y0 = blockIdx.y * BTH;
    const int c  = blockIdx.z;
    const f16_t* __restrict__ plane = in + (size_t)c * HWP;

    float k[13]; gauss13(k);

    // stage: 44 rows x 10 groups of 8 px; groups fully in- or out-of-bounds
    for (int idx = t; idx < RAWH * 10; idx += 256) {
        int row = idx / 10, g = idx - row * 10;
        int gy = y0 - 6 + row;
        int gx8 = x0 - 8 + g * 8;
        int4 u = {0, 0, 0, 0};
        if (gy >= 0 && gy < HH && gx8 >= 0 && gx8 <= WW - 8)
            u = *(const int4*)&plane[gy * WW + gx8];
        *(int4*)&rawh[row * RAWW + g * 8] = u;
    }
    __syncthreads();

    // h-pass: 44 rows x 16 groups of 4 outputs; read 20 f16 (5x b64)
    for (int idx = t; idx < RAWH * 16; idx += 256) {
        int row = idx >> 4, xg = idx & 15;
        const f16_t* rp = &rawh[row * RAWW + xg * 4];
        I2H4 fq[5];
#pragma unroll
        for (int q = 0; q < 5; ++q) fq[q].v = *(const int2*)&rp[q * 4];
        H4I2 o;
#pragma unroll
        for (int j = 0; j < 4; ++j) {
            float a = 0.f;
#pragma unroll
            for (int i = 0; i < 13; ++i) {
                int e = j + 2 + i;
                a = fmaf(k[i], (float)fq[e >> 2].h[e & 3], a);
            }
            o.h[j] = (f16_t)a;
        }
        *(int2*)&hbh[row * BTW + xg * 4] = o.v;
    }
    __syncthreads();

    // v-pass: each thread does 4 cols x 2 rows; 14 b64 reads, 2 b64 stores
    {
        const int xg = t & 15;          // 16 col-groups of 4
        const int yg = t >> 4;          // 16 row-groups of 2
        I2H4 r[14];
#pragma unroll
        for (int i = 0; i < 14; ++i)
            r[i].v = *(const int2*)&hbh[(yg * 2 + i) * BTW + xg * 4];
#pragma unroll
        for (int j = 0; j < 2; ++j) {
            float a0 = 0.f, a1 = 0.f, a2 = 0.f, a3 = 0.f;
#pragma unroll
            for (int i = 0; i < 13; ++i) {
                a0 = fmaf(k[i], (float)r[j + i].h[0], a0);
                a1 = fmaf(k[i], (float)r[j + i].h[1], a1);
                a2 = fmaf(k[i], (float)r[j + i].h[2], a2);
                a3 = fmaf(k[i], (float)r[j + i].h[3], a3);
            }
            H4I2 s;
            s.h[0] = (f16_t)a0; s.h[1] = (f16_t)a1; s.h[2] = (f16_t)a2; s.h[3] = (f16_t)a3;
            *(int2*)&out[(size_t)c * HWP + (y0 + yg * 2 + j) * WW + (x0 + xg * 4)] = s.v;
        }
    }
}

// ---------------------------------------------------------------------------
// Iteration tail. 32x8 tile / 256 threads. Channels-last f16 LDS window.
// Changes vs round 0: sp loads issued at kernel top (hidden under staging),
// weight+gather fused (no wnr[25] array), launch_bounds (256,4).
// ---------------------------------------------------------------------------
#define TTW 32
#define TTH 8
#define TWW (TTW + 4)         // 36
#define TWH (TTH + 4)         // 12
#define TWN (TWW * TWH)       // 432

template <bool LAST>
__global__ __launch_bounds__(256, 4) void tail_kernel(const int4* __restrict__ qcl4,
                                                      const f16_t* __restrict__ sp,
                                                      const float* __restrict__ img,
                                                      const f16_t* __restrict__ semLh,
                                                      const f16_t* __restrict__ insLh,
                                                      const float* __restrict__ sem_sw,
                                                      const float* __restrict__ sem_bw,
                                                      const float* __restrict__ sem_compat,
                                                      const float* __restrict__ ins_sw,
                                                      const float* __restrict__ ins_bw,
                                                      const int*   __restrict__ labels,
                                                      const float* __restrict__ cross_is,
                                                      const float* __restrict__ cross_si,
                                                      int4* __restrict__ qclo4,
                                                      f16_t* __restrict__ qpmo,
                                                      float* __restrict__ dout) {
    __shared__ int4  lqA[TWN * 3];       // 20736 B (channels 0..23)
    __shared__ int2  lqB[TWN];           //  3456 B (channels 24..27)
    __shared__ float limg[3 * TWN];      //  5184 B
    __shared__ float sC[NSEM * NSEM];
    __shared__ float sMis[NINS * NSEM];
    __shared__ float sMsi[NINS * NSEM];
    __shared__ float sws[NSEM], sbs[NSEM], swi[NINS], sbi[NINS];

    const int t  = threadIdx.x;
    const int tx = t & 31;
    const int ty = t >> 5;
    const int x0 = blockIdx.x * TTW;
    const int y0 = blockIdx.y * TTH;
    const int p  = (y0 + ty) * WW + (x0 + tx);

    // early-issue the 28 sp plane loads: they drain while we stage LDS
    f16_t spv[NCH];
#pragma unroll
    for (int c = 0; c < NCH; ++c) spv[c] = sp[c * HWP + p];

    if (t < NSEM * NSEM) sC[t] = sem_compat[t];
    if (t < NINS * NSEM) {
        int i = t / NSEM, o = t - i * NSEM;
        sMis[t] = cross_is[labels[i] * NSEM + o];
        sMsi[t] = cross_si[labels[i] * NSEM + o];  // [o_ins*12 + i_sem]
    }
    if (t < NSEM) { sws[t] = sem_sw[t]; sbs[t] = sem_bw[t]; }
    if (t < NINS) { int l = labels[t]; swi[t] = ins_sw[l]; sbi[t] = ins_bw[l]; }

    // stage q window, A-part: idx = e*3+s  (TWN*3 = 1296)
#pragma unroll
    for (int j = 0; j < 6; ++j) {
        int idx = t + j * 256;
        if (idx < TWN * 3) {
            int e = idx / 3, s = idx - e * 3;
            int ly = e / TWW, lx = e - ly * TWW;
            int gy = min(max(y0 - 2 + ly, 0), HH - 1);
            int gx = min(max(x0 - 2 + lx, 0), WW - 1);
            lqA[idx] = qcl4[(gy * WW + gx) * 4 + s];
        }
    }
    // B-part: channels 24..27 = int2 #6 of the 64-B record
#pragma unroll
    for (int j = 0; j < 2; ++j) {
        int e = t + j * 256;
        if (e < TWN) {
            int ly = e / TWW, lx = e - ly * TWW;
            int gy = min(max(y0 - 2 + ly, 0), HH - 1);
            int gx = min(max(x0 - 2 + lx, 0), WW - 1);
            lqB[e] = ((const int2*)qcl4)[(gy * WW + gx) * 8 + 6];
        }
    }
    // image window (fp32, edge-clamped)
    for (int idx = t; idx < 3 * TWN; idx += 256) {
        int cc  = idx / TWN;
        int rem = idx - cc * TWN;
        int ly  = rem / TWW, lx = rem - ly * TWW;
        int gy  = min(max(y0 - 2 + ly, 0), HH - 1);
        int gx  = min(max(x0 - 2 + lx, 0), WW - 1);
        limg[idx] = img[(size_t)cc * HWP + gy * WW + gx];
    }
    __syncthreads();

    // ---- fused bilateral: weight + gather + den in one 25-tap loop
    float num[NCH];
#pragma unroll
    for (int c = 0; c < NCH; ++c) num[c] = 0.f;
    float den = 0.f;
    {
        const int wc = (ty + 2) * TWW + (tx + 2);
        float i0 = limg[wc], i1 = limg[TWN + wc], i2 = limg[2 * TWN + wc];
#pragma unroll
        for (int dy = 0; dy < 5; ++dy) {
#pragma unroll
            for (int dx = 0; dx < 5; ++dx) {
                int e = (ty + dy) * TWW + (tx + dx);
                float d0 = limg[e] - i0;
                float d1 = limg[TWN + e] - i1;
                float d2 = limg[2 * TWN + e] - i2;
                float cd = d0 * d0 + d1 * d1 + d2 * d2;
                float sd = (float)((dy - 2) * (dy - 2) + (dx - 2) * (dx - 2));
                float w  = __expf(-sd * (1.f / 18.f) - cd * (1.f / 0.045f));
                den += w;
                I4H8 a0, a1, a2; I2H4 b;
                a0.v = lqA[e * 3 + 0]; a1.v = lqA[e * 3 + 1]; a2.v = lqA[e * 3 + 2];
                b.v  = lqB[e];
#pragma unroll
                for (int i = 0; i < 8; ++i) num[i]      = fmaf((float)a0.h[i], w, num[i]);
#pragma unroll
                for (int i = 0; i < 8; ++i) num[8 + i]  = fmaf((float)a1.h[i], w, num[8 + i]);
#pragma unroll
                for (int i = 0; i < 8; ++i) num[16 + i] = fmaf((float)a2.h[i], w, num[16 + i]);
#pragma unroll
                for (int i = 0; i < 4; ++i) num[24 + i] = fmaf((float)b.h[i],  w, num[24 + i]);
            }
        }
    }
    const float inv = 1.f / den;

    // ---- pointwise CRF tail (sp from early regs, logits f16 planes)
    float comb[NSEM];
#pragma unroll
    for (int i = 0; i < NSEM; ++i)
        comb[i] = sws[i] * (float)spv[i] + sbs[i] * (num[i] * inv);
    float ts[NSEM];
#pragma unroll
    for (int o = 0; o < NSEM; ++o) {
        float a = (float)semLh[o * HWP + p];
#pragma unroll
        for (int i = 0; i < NSEM; ++i) a = fmaf(sC[i * NSEM + o], comb[i], a);
        ts[o] = a;
    }
    float ti[NINS];
#pragma unroll
    for (int i = 0; i < NINS; ++i)
        ti[i] = (float)insLh[i * HWP + p] + swi[i] * (float)spv[NSEM + i] + sbi[i] * (num[NSEM + i] * inv);

    float sIns[NINS], sSem[NSEM];
    softmaxN<NINS>(ti, sIns);
    softmaxN<NSEM>(ts, sSem);

    float nts[NSEM];
#pragma unroll
    for (int o = 0; o < NSEM; ++o) {
        float a = ts[o];
#pragma unroll
        for (int i = 0; i < NINS; ++i) a = fmaf(sMis[i * NSEM + o], sIns[i], a);
        nts[o] = a;
    }
    float nti[NINS];
#pragma unroll
    for (int o = 0; o < NINS; ++o) {
        float a = ti[o];
#pragma unroll
        for (int i = 0; i < NSEM; ++i) a = fmaf(sMsi[o * NSEM + i], sSem[i], a);
        nti[o] = a;
    }

    float oq1[NSEM], oq2[NINS];
    softmaxN<NSEM>(nts, oq1);
    softmaxN<NINS>(nti, oq2);

    if (LAST) {
#pragma unroll
        for (int i = 0; i < NSEM; ++i) dout[i * HWP + p] = oq1[i];
#pragma unroll
        for (int i = 0; i < NINS; ++i) dout[(NSEM + i) * HWP + p] = oq2[i];
    } else {
        P32 pk;
#pragma unroll
        for (int i = 0; i < 32; ++i) pk.h[i] = (f16_t)0.f;
#pragma unroll
        for (int i = 0; i < NSEM; ++i) { f16_t h = (f16_t)oq1[i]; pk.h[i] = h; qpmo[i * HWP + p] = h; }
#pragma unroll
        for (int i = 0; i < NINS; ++i) { f16_t h = (f16_t)oq2[i]; pk.h[NSEM + i] = h; qpmo[(NSEM + i) * HWP + p] = h; }
#pragma unroll
        for (int j = 0; j < 4; ++j) qclo4[p * 4 + j] = pk.v[j];
    }
}

// ---------------------------------------------------------------------------
extern "C" void kernel_launch(void* const* d_in, const int* in_sizes, int n_in,
                              void* d_out, int out_size, void* d_ws, size_t ws_size,
                              hipStream_t stream) {
    const float* image      = (const float*)d_in[0];
    const float* semL       = (const float*)d_in[1];
    const float* insL       = (const float*)d_in[2];
    const int*   labels     = (const int*)  d_in[3];
    const float* sem_sw     = (const float*)d_in[4];
    const float* sem_bw     = (const float*)d_in[5];
    const float* sem_compat = (const float*)d_in[6];
    const float* ins_sw     = (const float*)d_in[7];
    const float* ins_bw     = (const float*)d_in[8];
    const float* cross_is   = (const float*)d_in[9];
    const float* cross_si   = (const float*)d_in[10];

    // Workspace: qclA | qclB | qpmA | qpmB | sp | semLh | insLh  (round-0 proven layout)
    char* ws = (char*)d_ws;
    int4*  qclA  = (int4*)ws;                                   ws += (size_t)HWP * 64;
    int4*  qclB  = (int4*)ws;                                   ws += (size_t)HWP * 64;
    f16_t* qpmA  = (f16_t*)ws;                                  ws += (size_t)NCH * HWP * 2;
    f16_t* qpmB  = (f16_t*)ws;                                  ws += (size_t)NCH * HWP * 2;
    f16_t* sp    = (f16_t*)ws;                                  ws += (size_t)NCH * HWP * 2;
    f16_t* semLh = (f16_t*)ws;                                  ws += (size_t)NSEM * HWP * 2;
    f16_t* insLh = (f16_t*)ws;

    const int PIX_BLOCKS = HWP / 256;  // 1200
    init_kernel<<<PIX_BLOCKS, 256, 0, stream>>>(semL, insL, qclA, qpmA, semLh, insLh);

    dim3 bgrid(WW / BTW, HH / BTH, NCH);    // 10 x 15 x 28
    dim3 tgrid(WW / TTW, HH / TTH);         // 20 x 60

    // iter 0: A -> B
    blur_fused_kernel<<<bgrid, 256, 0, stream>>>(qpmA, sp);
    tail_kernel<false><<<tgrid, 256, 0, stream>>>(qclA, sp, image, semLh, insLh,
                                                  sem_sw, sem_bw, sem_compat,
                                                  ins_sw, ins_bw, labels,
                                                  cross_is, cross_si, qclB, qpmB, nullptr);
    // iter 1: B -> A
    blur_fused_kernel<<<bgrid, 256, 0, stream>>>(qpmB, sp);
    tail_kernel<false><<<tgrid, 256, 0, stream>>>(qclB, sp, image, semLh, insLh,
                                                  sem_sw, sem_bw, sem_compat,
                                                  ins_sw, ins_bw, labels,
                                                  cross_is, cross_si, qclA, qpmA, nullptr);
    // iter 2: A -> d_out (fp32 plane-major)
    blur_fused_kernel<<<bgrid, 256, 0, stream>>>(qpmA, sp);
    tail_kernel<true><<<tgrid, 256, 0, stream>>>(qclA, sp, image, semLh, insLh,
                                                 sem_sw, sem_bw, sem_compat,
                                                 ins_sw, ins_bw, labels,
                                                 cross_is, cross_si, nullptr, nullptr, (float*)d_out);
}